// Round 1
// 1057.483 us; speedup vs baseline: 1.1544x; 1.1544x over previous
//
#include <hip/hip_runtime.h>
#include <stdint.h>

// ---------- helpers ----------
typedef __attribute__((ext_vector_type(8))) short bf16x8;
typedef __attribute__((ext_vector_type(4))) float f32x4;

__device__ __forceinline__ float b2f(unsigned short s) {
    unsigned int u = ((unsigned int)s) << 16;
    return __builtin_bit_cast(float, u);
}
__device__ __forceinline__ unsigned short f2b(float f) {
    unsigned int u = __builtin_bit_cast(unsigned int, f);
    u += 0x7FFFu + ((u >> 16) & 1u);   // RNE
    return (unsigned short)(u >> 16);
}
__device__ __forceinline__ void unpack8(uint4 u, float* o) {
    unsigned int a0 = u.x, a1 = u.y, a2 = u.z, a3 = u.w;
    o[0] = __builtin_bit_cast(float, a0 << 16);
    o[1] = __builtin_bit_cast(float, a0 & 0xffff0000u);
    o[2] = __builtin_bit_cast(float, a1 << 16);
    o[3] = __builtin_bit_cast(float, a1 & 0xffff0000u);
    o[4] = __builtin_bit_cast(float, a2 << 16);
    o[5] = __builtin_bit_cast(float, a2 & 0xffff0000u);
    o[6] = __builtin_bit_cast(float, a3 << 16);
    o[7] = __builtin_bit_cast(float, a3 & 0xffff0000u);
}

#define GLOAD_LDS16(g, l) __builtin_amdgcn_global_load_lds( \
    (const __attribute__((address_space(1))) unsigned int*)(g), \
    (__attribute__((address_space(3))) unsigned int*)(l), 16, 0, 0)

#define EPS_ATTN 1e-8f
#define LN_EPS 1e-5f
#define SCALE 0.0625f  // 256^-0.5

// ---------- prep: W3 in MFMA B-fragment order ----------
__global__ __launch_bounds__(256) void k_prep(const float* __restrict__ wk,
                                              const float* __restrict__ wv,
                                              unsigned short* __restrict__ W3) {
    int g = blockIdx.x * 256 + threadIdx.x;   // 131072
    int j = g & 7;
    int f = (g >> 3) & 1023;
    int stage = g >> 13;
    int p = f & 15, qq = (f >> 4) & 3, ntl = f >> 6;
    int kc = stage >> 1, half = stage & 1;
    int k = kc * 32 + qq * 8 + j;
    int n = half * 256 + ntl * 16 + p;
    float v = (n < 256) ? wk[k * 256 + n] : wv[k * 256 + (n - 256)];
    W3[g] = f2b(v);
}

// ---------- slot init ----------
__global__ __launch_bounds__(256) void k_init(const float* __restrict__ sm,
                                              const float* __restrict__ slv,
                                              const float* __restrict__ noise,
                                              float* __restrict__ slots) {
    int idx = blockIdx.x * 256 + threadIdx.x; // 131072
    int d = idx & 255;
    slots[idx] = sm[d] + expf(slv[d]) * noise[idx];
}

// ---------- fused LN(inputs) + K/V projection (bf16 MFMA, async B staging) ----------
// K written [bh][n][32] (rep-staged, coalesced). V written TRANSPOSED [bh][d][4096]
// directly from accumulators (8B stores, 32B/row segments).
__global__ __launch_bounds__(256, 2) void k_kv(
    const float* __restrict__ x, const float* __restrict__ lnw, const float* __restrict__ lnb,
    const unsigned short* __restrict__ W3, const float* __restrict__ bk, const float* __restrict__ bv,
    unsigned short* __restrict__ Kb, unsigned short* __restrict__ Vb) {
    __shared__ __align__(16) unsigned short sh[33792];  // 67,584 B
    unsigned short* As = sh;                  // 16384 ushorts (A frags, xor-swizzled)
    unsigned short* Bs = sh + 16384;          // 2 x 8192 ushorts (B dbuf)
    float* bL = (float*)(sh + 32768);         // 512 floats (biases)
    int t = threadIdx.x;
    int w = t >> 6, lane = t & 63;
    int p = lane & 15, q = lane >> 4;

    {
        const unsigned short* gp = W3 + (size_t)(w * 4) * 512 + lane * 8;
        #pragma unroll
        for (int c = 0; c < 4; ++c)
            GLOAD_LDS16(gp + c * 512, Bs + (w * 4 + c) * 512);
    }
    if (t < 128) {
        float4 bb = (t < 64) ? ((const float4*)bk)[t] : ((const float4*)bv)[t - 64];
        *(float4*)&bL[t * 4] = bb;
    }

    float4 lw  = ((const float4*)lnw)[lane];
    float4 lbv = ((const float4*)lnb)[lane];
    float4 xv[16];
    const float* xbase = x + ((size_t)blockIdx.x * 64 + w * 16) * 256;
    #pragma unroll
    for (int i = 0; i < 16; ++i) xv[i] = ((const float4*)(xbase + i * 256))[lane];
    int kcw = lane >> 3, qw = (lane >> 1) & 3, j0 = (lane & 1) * 4;
    #pragma unroll
    for (int i = 0; i < 16; ++i) {
        float4 v = xv[i];
        float s0 = v.x + v.y + v.z + v.w;
        float s1 = v.x * v.x + v.y * v.y + v.z * v.z + v.w * v.w;
        #pragma unroll
        for (int o = 1; o < 64; o <<= 1) { s0 += __shfl_xor(s0, o); s1 += __shfl_xor(s1, o); }
        float mean = s0 * (1.0f / 256.0f);
        float var  = s1 * (1.0f / 256.0f) - mean * mean;
        float rstd = rsqrtf(var + LN_EPS);
        ushort4 pk;
        pk.x = f2b((v.x - mean) * rstd * lw.x + lbv.x);
        pk.y = f2b((v.y - mean) * rstd * lw.y + lbv.y);
        pk.z = f2b((v.z - mean) * rstd * lw.z + lbv.z);
        pk.w = f2b((v.w - mean) * rstd * lw.w + lbv.w);
        int pos = (qw * 16 + i) ^ kcw;
        *(ushort4*)&As[((w * 8 + kcw) * 64 + pos) * 8 + j0] = pk;
    }
    __syncthreads();

    f32x4 acc[32];
    f32x4 zero = {0.f, 0.f, 0.f, 0.f};
    #pragma unroll
    for (int i = 0; i < 32; ++i) acc[i] = zero;

    for (int s1 = 0; s1 < 16; ++s1) {
        if (s1 < 15) {
            int nx = s1 + 1;
            const unsigned short* gp = W3 + (size_t)nx * 8192 + (w * 4) * 512 + lane * 8;
            unsigned short* lb = Bs + ((nx & 1) ? 8192 : 0);
            #pragma unroll
            for (int c = 0; c < 4; ++c)
                GLOAD_LDS16(gp + c * 512, lb + (w * 4 + c) * 512);
        }
        int kc = s1 >> 1, half = s1 & 1;
        bf16x8 af = *(const bf16x8*)&As[((w * 8 + kc) * 64 + ((q * 16 + p) ^ kc)) * 8];
        const unsigned short* bbuf = Bs + ((s1 & 1) ? 8192 : 0);
        #pragma unroll
        for (int ntl = 0; ntl < 16; ++ntl) {
            bf16x8 bf = *(const bf16x8*)&bbuf[ntl * 512 + lane * 8];
            acc[half * 16 + ntl] = __builtin_amdgcn_mfma_f32_16x16x32_bf16(
                af, bf, acc[half * 16 + ntl], 0, 0, 0);
        }
        __syncthreads();
    }

    unsigned short* rep = As;
    int b_   = blockIdx.x >> 6;
    int n0g  = (blockIdx.x & 63) * 64;

    // K half: rep staging for fully-coalesced [bh][n][32] writes
    #pragma unroll
    for (int al = 0; al < 16; ++al) {
        float bias = bL[al * 16 + p];
        int hl = al >> 1, dh = (al & 1) * 16 + p;
        #pragma unroll
        for (int r = 0; r < 4; ++r) {
            int nl = w * 16 + q * 4 + r;
            rep[(hl * 64 + nl) * 32 + dh] = f2b(acc[al][r] + bias);
        }
    }
    __syncthreads();
    #pragma unroll
    for (int i = 0; i < 8; ++i) {
        uint4 vd = *(const uint4*)&rep[(i * 256 + t) * 8];
        *(uint4*)(Kb + (((size_t)b_ * 8 + i) * 4096 + n0g) * 32 + t * 8) = vd;
    }
    // V half: direct transposed stores [bh][d][4096], 4 consecutive n per lane
    #pragma unroll
    for (int al = 0; al < 16; ++al) {
        float bias = bL[256 + al * 16 + p];
        int hl = al >> 1, dh = (al & 1) * 16 + p;
        ushort4 pk;
        pk.x = f2b(acc[16 + al][0] + bias);
        pk.y = f2b(acc[16 + al][1] + bias);
        pk.z = f2b(acc[16 + al][2] + bias);
        pk.w = f2b(acc[16 + al][3] + bias);
        *(ushort4*)(Vb + ((size_t)(b_ * 8 + hl) * 32 + dh) * 4096 + n0g + w * 16 + q * 4) = pk;
    }
}

// ---------- q projection ----------
__global__ __launch_bounds__(256) void k_q(
    const float* __restrict__ slots, const float* __restrict__ lnw, const float* __restrict__ lnb,
    const float* __restrict__ wq, const float* __restrict__ bq, float* __restrict__ qg) {
    __shared__ float sln[256];
    __shared__ float red[8];
    int t = threadIdx.x;
    int row = blockIdx.x;
    float v = slots[(size_t)row * 256 + t];
    float s0 = v, s1 = v * v;
    #pragma unroll
    for (int off = 1; off < 64; off <<= 1) { s0 += __shfl_xor(s0, off); s1 += __shfl_xor(s1, off); }
    if ((t & 63) == 0) { red[t >> 6] = s0; red[4 + (t >> 6)] = s1; }
    __syncthreads();
    float ts0 = red[0] + red[1] + red[2] + red[3];
    float ts1 = red[4] + red[5] + red[6] + red[7];
    float mean = ts0 * (1.f / 256.f);
    float var  = ts1 * (1.f / 256.f) - mean * mean;
    float rstd = rsqrtf(var + LN_EPS);
    sln[t] = (v - mean) * rstd * lnw[t] + lnb[t];
    __syncthreads();
    float acc = bq[t];
    #pragma unroll 4
    for (int k = 0; k < 256; ++k) acc += sln[k] * wq[k * 256 + t];
    int b = row >> 3, sl = row & 7;
    qg[(size_t)b * 2048 + (t >> 5) * 256 + sl * 32 + (t & 31)] = acc;
}

// ---------- attention sweep v2: MFMA QK^T (swapped) + MFMA PV, no main-loop LDS ----------
// grid 512 (one block per bh), 512 threads (8 waves), wave w owns n in [w*512, w*512+512).
// Per 32-n pair: 2x QK mfma (hi+lo Q split), 4+3 shfl softmax over s, 2x2 PV mfma
// (hi+lo attn split) with A = V^T loaded per-lane from the [bh][d][n] layout.
__global__ __launch_bounds__(512) void k_attn(
    const unsigned short* __restrict__ Kg, const unsigned short* __restrict__ VTg,
    const float* __restrict__ qg, float* __restrict__ upd_raw, float* __restrict__ rowsum,
    float* __restrict__ attn_out, int last) {
    __shared__ float supd[8][256];
    __shared__ float srs[8][8];
    int t = threadIdx.x;
    int w = t >> 6, lane = t & 63;
    int c = lane & 15;     // QK-C col = slot s ; PV A row = d ; PV-C col = s
    int g = lane >> 4;     // lane group

    int bh = blockIdx.x;
    const unsigned short* Kbh = Kg  + (size_t)bh * 4096 * 32;
    const unsigned short* Vbh = VTg + (size_t)bh * 32 * 4096;

    // Q B-fragment: lane holds Q[s=c][d=g*8+j], bf16 hi+lo split; zero for s>=8.
    bf16x8 qhi = {0,0,0,0,0,0,0,0};
    bf16x8 qlo = {0,0,0,0,0,0,0,0};
    if (c < 8) {
        const float* qp = qg + (size_t)bh * 256 + c * 32 + g * 8;
        #pragma unroll
        for (int j = 0; j < 8; ++j) {
            float qv = qp[j];
            unsigned short hb = f2b(qv);
            qhi[j] = (short)hb;
            qlo[j] = (short)f2b(qv - b2f(hb));
        }
    }

    f32x4 zero = {0.f, 0.f, 0.f, 0.f};
    f32x4 accL = zero, accH = zero;
    float rs = 0.f;
    int nb0 = w * 512;

    #pragma unroll 2
    for (int pr = 0; pr < 16; ++pr) {
        int base = nb0 + pr * 32;
        // K A-fragments: lane l <- K[base(+16)+c][g*8..g*8+7], 16B coalesced
        bf16x8 k0 = *(const bf16x8*)(Kbh + (size_t)(base + c) * 32 + g * 8);
        bf16x8 k1 = *(const bf16x8*)(Kbh + (size_t)(base + 16 + c) * 32 + g * 8);
        // V^T A-fragments: lane l <- VT[d=c(+16)][k-interleave], two 8B chunks each
        const unsigned short* vlo = Vbh + (size_t)c * 4096 + base + g * 4;
        const unsigned short* vhi = Vbh + (size_t)(c + 16) * 4096 + base + g * 4;
        union { ushort4 h[2]; bf16x8 v; } V0, V1;
        V0.h[0] = *(const ushort4*)vlo;
        V0.h[1] = *(const ushort4*)(vlo + 16);
        V1.h[0] = *(const ushort4*)vhi;
        V1.h[1] = *(const ushort4*)(vhi + 16);

        // dots^T: C[row = n-rel = g*4+r][col = s = c]
        f32x4 s0 = __builtin_amdgcn_mfma_f32_16x16x32_bf16(k0, qhi, zero, 0, 0, 0);
        s0 = __builtin_amdgcn_mfma_f32_16x16x32_bf16(k0, qlo, s0, 0, 0, 0);
        f32x4 s1 = __builtin_amdgcn_mfma_f32_16x16x32_bf16(k1, qhi, zero, 0, 0, 0);
        s1 = __builtin_amdgcn_mfma_f32_16x16x32_bf16(k1, qlo, s1, 0, 0, 0);

        float d0[4], d1[4];
        #pragma unroll
        for (int r = 0; r < 4; ++r) { d0[r] = s0[r] * SCALE; d1[r] = s1[r] * SCALE; }
        // group-wide max (same shift for every n in the pair -> valid softmax shift)
        float m = fmaxf(fmaxf(fmaxf(d0[0], d0[1]), fmaxf(d0[2], d0[3])),
                        fmaxf(fmaxf(d1[0], d1[1]), fmaxf(d1[2], d1[3])));
        m = fmaxf(m, __shfl_xor(m, 1));
        m = fmaxf(m, __shfl_xor(m, 2));
        m = fmaxf(m, __shfl_xor(m, 4));
        m = fmaxf(m, __shfl_xor(m, 8));
        float a0[4], a1[4];
        #pragma unroll
        for (int r = 0; r < 4; ++r) {
            float e0 = __expf(d0[r] - m);
            float e1 = __expf(d1[r] - m);
            // sum over s=0..7 (xor 1,2,4 stays inside the valid 8-lane subgroup)
            float t0 = e0;
            t0 += __shfl_xor(t0, 1); t0 += __shfl_xor(t0, 2); t0 += __shfl_xor(t0, 4);
            float t1 = e1;
            t1 += __shfl_xor(t1, 1); t1 += __shfl_xor(t1, 2); t1 += __shfl_xor(t1, 4);
            a0[r] = e0 * (1.0f / t0) + EPS_ATTN;
            a1[r] = e1 * (1.0f / t1) + EPS_ATTN;
            rs += a0[r] + a1[r];
        }
        if (last && c < 8) {
            float4 st0 = {a0[0], a0[1], a0[2], a0[3]};
            float4 st1 = {a1[0], a1[1], a1[2], a1[3]};
            float* ap = attn_out + ((size_t)bh * 8 + c) * 4096 + base + g * 4;
            *(float4*)ap = st0;
            *(float4*)(ap + 16) = st1;
        }
        // attn B-fragment (k-interleave matches V^T A-frag), bf16 hi+lo split
        bf16x8 pah, pal;
        float af[8] = {a0[0], a0[1], a0[2], a0[3], a1[0], a1[1], a1[2], a1[3]};
        #pragma unroll
        for (int j = 0; j < 8; ++j) {
            unsigned short hb = f2b(af[j]);
            pah[j] = (short)hb;
            pal[j] = (short)f2b(af[j] - b2f(hb));
        }
        accL = __builtin_amdgcn_mfma_f32_16x16x32_bf16(V0.v, pah, accL, 0, 0, 0);
        accL = __builtin_amdgcn_mfma_f32_16x16x32_bf16(V0.v, pal, accL, 0, 0, 0);
        accH = __builtin_amdgcn_mfma_f32_16x16x32_bf16(V1.v, pah, accH, 0, 0, 0);
        accH = __builtin_amdgcn_mfma_f32_16x16x32_bf16(V1.v, pal, accH, 0, 0, 0);
    }

    // rowsum: combine the 4 lane-groups (same s, disjoint n)
    rs += __shfl_xor(rs, 16);
    rs += __shfl_xor(rs, 32);
    if (lane < 8) srs[w][lane] = rs;
    // upd^T: lane holds D[d = g*4+r (+16)][s = c], valid for c<8
    if (c < 8) {
        float* up = &supd[w][c * 32 + g * 4];
        up[0]  = accL[0]; up[1]  = accL[1]; up[2]  = accL[2]; up[3]  = accL[3];
        up[16] = accH[0]; up[17] = accH[1]; up[18] = accH[2]; up[19] = accH[3];
    }
    __syncthreads();
    if (t < 256) {
        float v = 0.f;
        #pragma unroll
        for (int ww = 0; ww < 8; ++ww) v += supd[ww][t];
        upd_raw[(size_t)bh * 256 + t] = v;
    }
    if (t < 8) {
        float v = 0.f;
        #pragma unroll
        for (int ww = 0; ww < 8; ++ww) v += srs[ww][t];
        rowsum[bh * 8 + t] = v;
    }
}

// ========== slot-update stage kernels (col-split, LDS row-broadcast) ==========
// Stage A: O = U @ wo + bo.  grid 256 = b(64) x cc(4); 64 cols/block, K split 4 ways over waves.
__global__ __launch_bounds__(256) void k_gA(
    const float* __restrict__ upd_raw, const float* __restrict__ rowsum,
    const float* __restrict__ wo, const float* __restrict__ bo, float* __restrict__ O) {
    __shared__ float Ul[8][256];
    __shared__ float Pp[4][8][64];
    int t = threadIdx.x;
    int b = blockIdx.x >> 2, cc = blockIdx.x & 3;
    int colbase = cc * 64;
    {
        int r = t >> 5, d0 = (t & 31) * 8;
        int h = d0 >> 5;
        float inv = 1.0f / fmaxf(rowsum[(b * 8 + h) * 8 + r], 1e-12f);
        const float* up = upd_raw + (size_t)(b * 8 + h) * 256 + r * 32 + (d0 & 31);
        float4 u0 = *(const float4*)up;
        float4 u1 = *(const float4*)(up + 4);
        Ul[r][d0 + 0] = u0.x * inv; Ul[r][d0 + 1] = u0.y * inv;
        Ul[r][d0 + 2] = u0.z * inv; Ul[r][d0 + 3] = u0.w * inv;
        Ul[r][d0 + 4] = u1.x * inv; Ul[r][d0 + 5] = u1.y * inv;
        Ul[r][d0 + 6] = u1.z * inv; Ul[r][d0 + 7] = u1.w * inv;
    }
    __syncthreads();
    int c = t & 63, kq = t >> 6;
    float acc[8] = {0.f,0.f,0.f,0.f,0.f,0.f,0.f,0.f};
    const float* wp = wo + (size_t)(kq * 64) * 256 + colbase + c;
    #pragma unroll 16
    for (int k = 0; k < 64; ++k) {
        float wv_ = wp[(size_t)k * 256];
        int kk = kq * 64 + k;
        #pragma unroll
        for (int r = 0; r < 8; ++r) acc[r] += Ul[r][kk] * wv_;
    }
    #pragma unroll
    for (int r = 0; r < 8; ++r) Pp[kq][r][c] = acc[r];
    __syncthreads();
    #pragma unroll
    for (int j = 0; j < 2; ++j) {
        int o = t * 2 + j;
        int r = o >> 6, c2 = o & 63;
        float v = Pp[0][r][c2] + Pp[1][r][c2] + Pp[2][r][c2] + Pp[3][r][c2] + bo[colbase + c2];
        O[(size_t)(b * 8 + r) * 256 + colbase + c2] = v;
    }
}

// Stage B: xg = O@wih+bih, hg = Hp@whh+bhh. grid 384 = b(64) x cc(6); 128 cols/block, K split 2.
// cols 0..511 -> gcomb (xr+hr, xz+hz); cols 512..767 -> xn, hn separate.
__global__ __launch_bounds__(256) void k_gB(
    const float* __restrict__ O, const float* __restrict__ slin,
    const float* __restrict__ wih, const float* __restrict__ bih,
    const float* __restrict__ whh, const float* __restrict__ bhh,
    float* __restrict__ gcomb, float* __restrict__ xn, float* __restrict__ hn) {
    __shared__ float Ol[8][256], Hl[8][256];
    __shared__ float Px[2][8][128], Ph[2][8][128];
    int t = threadIdx.x;
    int b = blockIdx.x / 6, cc = blockIdx.x % 6;
    int colbase = cc * 128;
    {
        int r = t >> 5, d0 = (t & 31) * 8;
        const float* op = O + (size_t)(b * 8 + r) * 256 + d0;
        const float* hp = slin + (size_t)(b * 8 + r) * 256 + d0;
        *(float4*)&Ol[r][d0]     = *(const float4*)op;
        *(float4*)&Ol[r][d0 + 4] = *(const float4*)(op + 4);
        *(float4*)&Hl[r][d0]     = *(const float4*)hp;
        *(float4*)&Hl[r][d0 + 4] = *(const float4*)(hp + 4);
    }
    __syncthreads();
    int c = t & 127, kh = t >> 7;
    float ax[8] = {0.f,0.f,0.f,0.f,0.f,0.f,0.f,0.f};
    float ah[8] = {0.f,0.f,0.f,0.f,0.f,0.f,0.f,0.f};
    const float* wxp = wih + (size_t)(kh * 128) * 768 + colbase + c;
    const float* whp = whh + (size_t)(kh * 128) * 768 + colbase + c;
    #pragma unroll 8
    for (int k = 0; k < 128; ++k) {
        float wx = wxp[(size_t)k * 768];
        float wh = whp[(size_t)k * 768];
        int kk = kh * 128 + k;
        #pragma unroll
        for (int r = 0; r < 8; ++r) { ax[r] += Ol[r][kk] * wx; ah[r] += Hl[r][kk] * wh; }
    }
    #pragma unroll
    for (int r = 0; r < 8; ++r) { Px[kh][r][c] = ax[r]; Ph[kh][r][c] = ah[r]; }
    __syncthreads();
    #pragma unroll
    for (int j = 0; j < 4; ++j) {
        int o = t * 4 + j;               // [0,1024)
        int r = o >> 7, c2 = o & 127;
        int cg = colbase + c2;
        int row = b * 8 + r;
        float vx = Px[0][r][c2] + Px[1][r][c2] + bih[cg];
        float vh = Ph[0][r][c2] + Ph[1][r][c2] + bhh[cg];
        if (cg < 512) {
            gcomb[(size_t)row * 512 + cg] = vx + vh;
        } else {
            xn[(size_t)row * 256 + cg - 512] = vx;
            hn[(size_t)row * 256 + cg - 512] = vh;
        }
    }
}

// Stage C: gates -> S1 (stored into slout), LN(S1) -> F.  grid 512 rows.
__global__ __launch_bounds__(256) void k_gC(
    const float* __restrict__ gcomb, const float* __restrict__ xn, const float* __restrict__ hn,
    const float* __restrict__ slin, const float* __restrict__ lnfw, const float* __restrict__ lnfb,
    float* __restrict__ slout, float* __restrict__ F) {
    __shared__ float red[8];
    int t = threadIdx.x, row = blockIdx.x;
    float a_r = gcomb[(size_t)row * 512 + t];
    float a_z = gcomb[(size_t)row * 512 + 256 + t];
    float xnv = xn[(size_t)row * 256 + t];
    float hnv = hn[(size_t)row * 256 + t];
    float hp  = slin[(size_t)row * 256 + t];
    float rg = 1.f / (1.f + expf(-a_r));
    float zg = 1.f / (1.f + expf(-a_z));
    float ng = tanhf(xnv + rg * hnv);
    float s1 = (1.f - zg) * ng + zg * hp;
    slout[(size_t)row * 256 + t] = s1;
    float s0 = s1, sq = s1 * s1;
    #pragma unroll
    for (int o = 1; o < 64; o <<= 1) { s0 += __shfl_xor(s0, o); sq += __shfl_xor(sq, o); }
    if ((t & 63) == 0) { red[t >> 6] = s0; red[4 + (t >> 6)] = sq; }
    __syncthreads();
    float ts0 = red[0] + red[1] + red[2] + red[3];
    float ts1 = red[4] + red[5] + red[6] + red[7];
    float mean = ts0 * (1.f / 256.f);
    float var  = ts1 * (1.f / 256.f) - mean * mean;
    float rstd = rsqrtf(var + LN_EPS);
    F[(size_t)row * 256 + t] = (s1 - mean) * rstd * lnfw[t] + lnfb[t];
}

// Stage D: H1 = relu(F @ w1 + b1).  grid 256 = b x cc(4).
__global__ __launch_bounds__(256) void k_gD(
    const float* __restrict__ F, const float* __restrict__ w1, const float* __restrict__ b1,
    float* __restrict__ H1) {
    __shared__ float Fl[8][256];
    __shared__ float Pp[4][8][64];
    int t = threadIdx.x;
    int b = blockIdx.x >> 2, cc = blockIdx.x & 3;
    int colbase = cc * 64;
    {
        int r = t >> 5, d0 = (t & 31) * 8;
        const float* fp = F + (size_t)(b * 8 + r) * 256 + d0;
        *(float4*)&Fl[r][d0]     = *(const float4*)fp;
        *(float4*)&Fl[r][d0 + 4] = *(const float4*)(fp + 4);
    }
    __syncthreads();
    int c = t & 63, kq = t >> 6;
    float acc[8] = {0.f,0.f,0.f,0.f,0.f,0.f,0.f,0.f};
    const float* wp = w1 + (size_t)(kq * 64) * 256 + colbase + c;
    #pragma unroll 16
    for (int k = 0; k < 64; ++k) {
        float wv_ = wp[(size_t)k * 256];
        int kk = kq * 64 + k;
        #pragma unroll
        for (int r = 0; r < 8; ++r) acc[r] += Fl[r][kk] * wv_;
    }
    #pragma unroll
    for (int r = 0; r < 8; ++r) Pp[kq][r][c] = acc[r];
    __syncthreads();
    #pragma unroll
    for (int j = 0; j < 2; ++j) {
        int o = t * 2 + j;
        int r = o >> 6, c2 = o & 63;
        float v = Pp[0][r][c2] + Pp[1][r][c2] + Pp[2][r][c2] + Pp[3][r][c2] + b1[colbase + c2];
        H1[(size_t)(b * 8 + r) * 256 + colbase + c2] = fmaxf(v, 0.f);
    }
}

// Stage E: slout = S1 + H1 @ w2 + b2 (S1 already resident in slout).  grid 256.
__global__ __launch_bounds__(256) void k_gE(
    const float* __restrict__ H1, const float* __restrict__ w2, const float* __restrict__ b2,
    float* __restrict__ slout) {
    __shared__ float Hl[8][256];
    __shared__ float Pp[4][8][64];
    int t = threadIdx.x;
    int b = blockIdx.x >> 2, cc = blockIdx.x & 3;
    int colbase = cc * 64;
    {
        int r = t >> 5, d0 = (t & 31) * 8;
        const float* hp = H1 + (size_t)(b * 8 + r) * 256 + d0;
        *(float4*)&Hl[r][d0]     = *(const float4*)hp;
        *(float4*)&Hl[r][d0 + 4] = *(const float4*)(hp + 4);
    }
    __syncthreads();
    int c = t & 63, kq = t >> 6;
    float acc[8] = {0.f,0.f,0.f,0.f,0.f,0.f,0.f,0.f};
    const float* wp = w2 + (size_t)(kq * 64) * 256 + colbase + c;
    #pragma unroll 16
    for (int k = 0; k < 64; ++k) {
        float wv_ = wp[(size_t)k * 256];
        int kk = kq * 64 + k;
        #pragma unroll
        for (int r = 0; r < 8; ++r) acc[r] += Hl[r][kk] * wv_;
    }
    #pragma unroll
    for (int r = 0; r < 8; ++r) Pp[kq][r][c] = acc[r];
    __syncthreads();
    #pragma unroll
    for (int j = 0; j < 2; ++j) {
        int o = t * 2 + j;
        int r = o >> 6, c2 = o & 63;
        size_t idx = (size_t)(b * 8 + r) * 256 + colbase + c2;
        float v = Pp[0][r][c2] + Pp[1][r][c2] + Pp[2][r][c2] + Pp[3][r][c2] + b2[colbase + c2];
        slout[idx] = slout[idx] + v;
    }
}

// ---------- final attn normalization ----------
__global__ __launch_bounds__(256) void k_scale(float* __restrict__ attn, const float* __restrict__ rowsum) {
    size_t idx = (size_t)blockIdx.x * 256 + threadIdx.x;
    int row = (int)(idx >> 12);
    float rs = fmaxf(rowsum[row], 1e-12f);
    attn[idx] = attn[idx] / rs;
}

extern "C" void kernel_launch(void* const* d_in, const int* in_sizes, int n_in,
                              void* d_out, int out_size, void* d_ws, size_t ws_size,
                              hipStream_t stream) {
    const float* inputs = (const float*)d_in[0];
    const float* noise  = (const float*)d_in[1];
    const float* sm     = (const float*)d_in[2];
    const float* slv    = (const float*)d_in[3];
    const float* wq     = (const float*)d_in[4];
    const float* bq     = (const float*)d_in[5];
    const float* wk     = (const float*)d_in[6];
    const float* bk     = (const float*)d_in[7];
    const float* wv     = (const float*)d_in[8];
    const float* bv     = (const float*)d_in[9];
    const float* wo     = (const float*)d_in[10];
    const float* bo     = (const float*)d_in[11];
    const float* wih    = (const float*)d_in[12];
    const float* bih    = (const float*)d_in[13];
    const float* whh    = (const float*)d_in[14];
    const float* bhh    = (const float*)d_in[15];
    const float* w1     = (const float*)d_in[16];
    const float* b1     = (const float*)d_in[17];
    const float* w2     = (const float*)d_in[18];
    const float* b2     = (const float*)d_in[19];
    const float* lniw   = (const float*)d_in[20];
    const float* lnib   = (const float*)d_in[21];
    const float* lnsw   = (const float*)d_in[22];
    const float* lnsb   = (const float*)d_in[23];
    const float* lnfw   = (const float*)d_in[24];
    const float* lnfb   = (const float*)d_in[25];

    // ws layout (~273.2 MB), with aliasing:
    //  P region: W3 (prep/kv) then O (gA->gB)
    //  Q region: gcomb+xn+hn (gB->gC) then H1 (gD->gE)
    //  R region: qg (k_q->k_attn) then F (gC->gD)
    char* ws = (char*)d_ws;
    unsigned short* Kb = (unsigned short*)ws;                         // 134,217,728  [bh][n][32]
    unsigned short* Vb = (unsigned short*)(ws + 134217728ull);        // 134,217,728  [bh][d][4096] (transposed)
    float* slotsA  = (float*)(ws + 268435456ull);                     // 524,288
    float* slotsB  = (float*)(ws + 268959744ull);                     // 524,288
    float* Rr      = (float*)(ws + 269484032ull);                     // 524,288  (qg / F)
    float* Pr      = (float*)(ws + 270008320ull);                     // 524,288  (W3 / O)
    float* Qr      = (float*)(ws + 270532608ull);                     // 2,097,152 (gcomb|xn|hn / H1)
    float* upd_raw = (float*)(ws + 272629760ull);                     // 524,288
    float* rowsum  = (float*)(ws + 273154048ull);                     // 16,384
    unsigned short* W3 = (unsigned short*)Pr;
    float* O_  = Pr;
    float* gcomb = Qr;                    // 512x512
    float* xn = Qr + 262144;              // 512x256
    float* hn = Qr + 393216;              // 512x256
    float* H1 = Qr;                       // 512x256 (aliases gcomb, gB->gC dead by gD)
    float* qg = Rr;
    float* F_ = Rr;

    float* out_slots = (float*)d_out;            // [64,8,256]
    float* attn_out  = (float*)d_out + 131072;   // [64,8,8,4096]

    k_prep<<<512, 256, 0, stream>>>(wk, wv, W3);
    k_init<<<512, 256, 0, stream>>>(sm, slv, noise, slotsA);
    k_kv<<<4096, 256, 0, stream>>>(inputs, lniw, lnib, W3, bk, bv, Kb, Vb);
    for (int it = 0; it < 3; ++it) {
        int last = (it == 2);
        float* sl_in  = (it == 0) ? slotsA : ((it == 1) ? slotsB : slotsA);
        float* sl_out = (it == 0) ? slotsB : ((it == 1) ? slotsA : out_slots);
        k_q<<<512, 256, 0, stream>>>(sl_in, lnsw, lnsb, wq, bq, qg);
        k_attn<<<512, 512, 0, stream>>>(Kb, Vb, qg, upd_raw, rowsum, attn_out, last);
        k_gA<<<256, 256, 0, stream>>>(upd_raw, rowsum, wo, bo, O_);
        k_gB<<<384, 256, 0, stream>>>(O_, sl_in, wih, bih, whh, bhh, gcomb, xn, hn);
        k_gC<<<512, 256, 0, stream>>>(gcomb, xn, hn, sl_in, lnfw, lnfb, sl_out, F_);
        k_gD<<<256, 256, 0, stream>>>(F_, w1, b1, H1);
        k_gE<<<256, 256, 0, stream>>>(H1, w2, b2, sl_out);
    }
    k_scale<<<65536, 256, 0, stream>>>(attn_out, rowsum);
}